// Round 12
// baseline (323.408 us; speedup 1.0000x reference)
//
#include <hip/hip_runtime.h>
#include <hip/hip_bf16.h>
#include <math.h>

// ============================================================================
// StylePredictor. Round 12: split-stage pipeline (global->reg loads issued
// BEFORE compute, ds_write after) in gemm/qkv/conv/attn so L2 latency hides
// under MFMA work. Structure otherwise identical to round 11.
// ============================================================================

#define DEV __device__ __forceinline__

static constexpr int B_ = 16, T_ = 1024, D_ = 256;
static constexpr int N_ = B_ * T_;

typedef __attribute__((ext_vector_type(8))) short bf16x8;
typedef __attribute__((ext_vector_type(16))) float floatx16;

DEV float sigmoidf_(float x) { return 1.f / (1.f + __expf(-x)); }
// mish(x) = x*tanh(softplus(x)) = x * t/(t+2), t = u*(u+2), u = e^x
DEV float mishf_(float x) {
  float u = __expf(fminf(x, 30.f));
  float t = u * (u + 2.f);
  return x * (t / (t + 2.f));
}
DEV ushort f2bf_(float x) {
  __hip_bfloat16 h = __float2bfloat16(x);
  return *(ushort*)&h;
}

// ---------------------------------------------------------------------------
// Mega-prep (unchanged from round 11).
// ---------------------------------------------------------------------------
__global__ __launch_bounds__(256) void prep_all_kernel(
    const unsigned* __restrict__ mraw,
    const float* __restrict__ W1, const float* __restrict__ W2,
    const float* __restrict__ Wq, const float* __restrict__ Wk,
    const float* __restrict__ Wv, const float* __restrict__ Wo,
    const float* __restrict__ cW1, const float* __restrict__ cW2,
    ushort* __restrict__ w1, ushort* __restrict__ w2,
    ushort* __restrict__ wqkv, ushort* __restrict__ wo,
    ushort* __restrict__ WtF1, ushort* __restrict__ WtF2,
    float* __restrict__ fmask, ushort* __restrict__ QF,
    ushort* __restrict__ KF, float* __restrict__ pooled) {
  int bid = blockIdx.x, tid = threadIdx.x;
  if (bid < 384) {
    int i = bid * 256 + tid;  // 0..98303
    int widx = i >> 14, r = i & 16383;
    const float* src;
    ushort* dst;
    switch (widx) {
      case 0: src = W1; dst = w1; break;
      case 1: src = W2; dst = w2; break;
      case 2: src = Wq; dst = wqkv; break;
      case 3: src = Wk; dst = wqkv + 65536; break;
      case 4: src = Wv; dst = wqkv + 131072; break;
      default: src = Wo; dst = wo; break;
    }
    float4 v = ((const float4*)src)[r];
    ushort4 u;
    u.x = f2bf_(v.x); u.y = f2bf_(v.y); u.z = f2bf_(v.z); u.w = f2bf_(v.w);
    ((ushort4*)dst)[r] = u;
  } else if (bid < 1024) {
    int idx = (bid - 384) * 256 + tid;  // 0..163839 (ushort8 granules)
    const float* cw = (idx < 81920) ? cW1 : cW2;
    ushort* dst = (idx < 81920) ? WtF1 : WtF2;
    int i8 = (idx < 81920) ? idx : idx - 81920;
    int i = i8 * 8;
    int half = (i >> 3) & 1, m31 = (i >> 4) & 31;
    int frag = i >> 9;
    int ks = frag & 1, c = (frag >> 1) & 7, tap = (frag >> 4) % 5,
        cot = frag / 80;
    int co = cot * 32 + m31;
    int cin0 = c * 32 + ks * 16 + half * 8;
    ushort u[8];
#pragma unroll
    for (int j = 0; j < 8; ++j)
      u[j] = f2bf_(cw[(size_t)(co * 256 + cin0 + j) * 5 + tap]);
    *(uint4*)&dst[i] = *(uint4*)u;
  } else {
    // mask detection + fmask + QF/KF bias chunks + pooled zero
    int isByte = 0, isFloat = 0;
    for (int i = 0; i < 16; ++i) {
      unsigned v = mraw[tid * 16 + i];
      if (v == 0x3F800000u) isFloat = 1;
      else if (v > 1u) isByte = 1;
    }
    __shared__ int sByte, sFloat;
    if (tid == 0) { sByte = 0; sFloat = 0; }
    __syncthreads();
    if (isByte) atomicOr(&sByte, 1);
    if (isFloat) atomicOr(&sFloat, 1);
    __syncthreads();
    int mode = sFloat ? 2 : (sByte ? 1 : 0);
    int mb = bid - 1024;                 // 0..127
    int id = mb * 256 + tid;             // bh*1024 + t
    int bh = id >> 10, t = id & 1023, b = bh >> 1;
    int gidx = b * 1024 + t;
    unsigned mv;
    if (mode == 1) mv = ((const unsigned char*)mraw)[gidx];
    else           mv = mraw[gidx];
    float fm = (mv != 0u) ? 1.f : 0.f;
    if ((bh & 1) == 0) fmask[gidx] = fm;
    if (mb < 16) pooled[mb * 256 + tid] = 0.f;
    size_t qb = ((size_t)(bh * 32 + (t >> 5)) * 9 + 8) * 512 + (t & 31) * 16;
    QF[qb] = f2bf_(1.f);
#pragma unroll
    for (int j = 1; j < 16; ++j) QF[qb + j] = 0;
    size_t kb = ((size_t)(bh * 32 + (t >> 5)) * 9 + 8) * 512 + (t & 31) * 16;
    KF[kb] = (fm != 0.f) ? f2bf_(-60000.f) : (ushort)0;
#pragma unroll
    for (int j = 1; j < 16; ++j) KF[kb + j] = 0;
  }
}

// ---------------------------------------------------------------------------
// bf16 MFMA GEMM, BK=64, split-stage pipeline. Block = 32 rows x 128 cols,
// grid (512, 2). OMODE: 0=f32, 1=bf16, 2=both, 3=masked-pool.
// ---------------------------------------------------------------------------
template <int ACT, int RESID, int OMODE, int AF32>
__global__ __launch_bounds__(256, 4) void gemm_mfma_kernel(
    const void* __restrict__ Av, const ushort* __restrict__ W16,
    const float* __restrict__ bias, const float* __restrict__ resid,
    const float* __restrict__ fmask,
    float* __restrict__ outf, ushort* __restrict__ outb) {
  __shared__ __align__(16) ushort As[2][32 * 72];
  int tid = threadIdx.x;
  int w = tid >> 6, lane = tid & 63;
  int m31 = lane & 31, half = lane >> 5;
  int n0 = blockIdx.x * 32;
  int col = blockIdx.y * 128 + w * 32 + m31;
  const ushort* A16 = (const ushort*)Av;
  const float* A32 = (const float*)Av;
  int srow = tid >> 3, spart = tid & 7;

  floatx16 acc;
#pragma unroll
  for (int i = 0; i < 16; ++i) acc[i] = 0.f;

  uint4 areg;
  float4 af0, af1;
  auto loadA = [&](int k0) {
    if (AF32) {
      af0 = *(const float4*)&A32[(size_t)(n0 + srow) * 256 + k0 + spart * 8];
      af1 = *(const float4*)&A32[(size_t)(n0 + srow) * 256 + k0 + spart * 8 + 4];
    } else {
      areg = *(const uint4*)&A16[(size_t)(n0 + srow) * 256 + k0 + spart * 8];
    }
  };
  auto writeA = [&](int buf) {
    if (AF32) {
      ushort u[8];
      u[0] = f2bf_(af0.x); u[1] = f2bf_(af0.y); u[2] = f2bf_(af0.z); u[3] = f2bf_(af0.w);
      u[4] = f2bf_(af1.x); u[5] = f2bf_(af1.y); u[6] = f2bf_(af1.z); u[7] = f2bf_(af1.w);
      *(uint4*)&As[buf][srow * 72 + spart * 8] = *(uint4*)u;
    } else {
      *(uint4*)&As[buf][srow * 72 + spart * 8] = areg;
    }
  };
  loadA(0);
  writeA(0);
  bf16x8 bn[4];
#pragma unroll
  for (int ks = 0; ks < 4; ++ks)
    bn[ks] = *(const bf16x8*)&W16[(size_t)col * 256 + ks * 16 + half * 8];

  for (int c = 0; c < 4; ++c) {
    __syncthreads();
    if (c < 3) loadA((c + 1) * 64);      // issue loads early
    bf16x8 bc[4] = {bn[0], bn[1], bn[2], bn[3]};
    if (c < 3) {
      int k0 = (c + 1) * 64;
#pragma unroll
      for (int ks = 0; ks < 4; ++ks)
        bn[ks] = *(const bf16x8*)&W16[(size_t)col * 256 + k0 + ks * 16 + half * 8];
    }
    const ushort* ab = As[c & 1];
#pragma unroll
    for (int ks = 0; ks < 4; ++ks) {
      bf16x8 af = *(const bf16x8*)&ab[m31 * 72 + ks * 16 + half * 8];
      acc = __builtin_amdgcn_mfma_f32_32x32x16_bf16(af, bc[ks], acc, 0, 0, 0);
    }
    if (c < 3) writeA((c + 1) & 1);      // write after compute
  }
  float bv = bias[col];
  if (OMODE == 3) {
    int b = n0 >> 10;
    float psum = 0.f;
#pragma unroll
    for (int reg = 0; reg < 16; ++reg) {
      int row = n0 + (reg & 3) + 8 * (reg >> 2) + 4 * half;
      float keep = (fmask[row] == 0.f) ? 1.f : 0.f;
      psum += keep * (acc[reg] + bv + resid[(size_t)row * 256 + col]);
    }
    atomicAdd(&outf[b * 256 + col], psum);
    return;
  }
#pragma unroll
  for (int reg = 0; reg < 16; ++reg) {
    int row = n0 + (reg & 3) + 8 * (reg >> 2) + 4 * half;
    float v = acc[reg] + bv;
    if (ACT == 1) v = mishf_(v);
    if (RESID) v += resid[(size_t)row * 256 + col];
    if (OMODE == 0) {
      outf[(size_t)row * 256 + col] = v;
    } else if (OMODE == 1) {
      outb[(size_t)row * 256 + col] = f2bf_(v);
    } else {
      outf[(size_t)row * 256 + col] = v;
      outb[(size_t)row * 256 + col] = f2bf_(v);
    }
  }
}

// ---------------------------------------------------------------------------
// Fused QKV projection, BK=64, split-stage. grid (512, 2, 3).
// ---------------------------------------------------------------------------
__global__ __launch_bounds__(256, 4) void qkv_mfma_kernel(
    const ushort* __restrict__ A16, const ushort* __restrict__ wqkv,
    const float* __restrict__ bq, const float* __restrict__ bk,
    const float* __restrict__ bv,
    ushort* __restrict__ QF, ushort* __restrict__ KF, ushort* __restrict__ VF) {
  __shared__ __align__(16) ushort As[2][32 * 72];
  __shared__ __align__(16) ushort Tw[4][32 * 40];
  int tid = threadIdx.x;
  int w = tid >> 6, lane = tid & 63;
  int m31 = lane & 31, half = lane >> 5;
  int n0 = blockIdx.x * 32;
  int by = blockIdx.z;
  const ushort* W16 = wqkv + (size_t)by * 65536;
  const float* bias = (by == 0) ? bq : (by == 1) ? bk : bv;
  int col = blockIdx.y * 128 + w * 32 + m31;
  int srow = tid >> 3, spart = tid & 7;

  floatx16 acc;
#pragma unroll
  for (int i = 0; i < 16; ++i) acc[i] = 0.f;

  uint4 areg = *(const uint4*)&A16[(size_t)(n0 + srow) * 256 + spart * 8];
  *(uint4*)&As[0][srow * 72 + spart * 8] = areg;
  bf16x8 bn[4];
#pragma unroll
  for (int ks = 0; ks < 4; ++ks)
    bn[ks] = *(const bf16x8*)&W16[(size_t)col * 256 + ks * 16 + half * 8];

  for (int c = 0; c < 4; ++c) {
    __syncthreads();
    if (c < 3) {
      int k0 = (c + 1) * 64;
      areg = *(const uint4*)&A16[(size_t)(n0 + srow) * 256 + k0 + spart * 8];
    }
    bf16x8 bc[4] = {bn[0], bn[1], bn[2], bn[3]};
    if (c < 3) {
      int k0 = (c + 1) * 64;
#pragma unroll
      for (int ks = 0; ks < 4; ++ks)
        bn[ks] = *(const bf16x8*)&W16[(size_t)col * 256 + k0 + ks * 16 + half * 8];
    }
    const ushort* ab = As[c & 1];
#pragma unroll
    for (int ks = 0; ks < 4; ++ks) {
      bf16x8 af = *(const bf16x8*)&ab[m31 * 72 + ks * 16 + half * 8];
      acc = __builtin_amdgcn_mfma_f32_32x32x16_bf16(af, bc[ks], acc, 0, 0, 0);
    }
    if (c < 3) *(uint4*)&As[(c + 1) & 1][srow * 72 + spart * 8] = areg;
  }
  int b = n0 >> 10;
  float bvv = bias[col];
  int h = col >> 7, d127 = col & 127;
  int bh = b * 2 + h;
  if (by == 2) {  // VF frag-major, ushort4 stores (already coalesced)
    int ctv = d127 >> 5, m31v = d127 & 31;
#pragma unroll
    for (int rg = 0; rg < 4; ++rg) {
      int t0 = (n0 & 1023) + 8 * rg + 4 * half;
      ushort4 u;
      u.x = f2bf_(acc[rg * 4 + 0] + bvv);
      u.y = f2bf_(acc[rg * 4 + 1] + bvv);
      u.z = f2bf_(acc[rg * 4 + 2] + bvv);
      u.w = f2bf_(acc[rg * 4 + 3] + bvv);
      size_t addr = ((size_t)(bh * 16 + (t0 >> 6)) * 16 +
                     ((t0 >> 4) & 3) * 4 + ctv) * 512 +
                    m31v * 16 + ((t0 >> 3) & 1) * 8 + (t0 & 7);
      *(ushort4*)&VF[addr] = u;
    }
  } else {
    float scale = (by == 0) ? 0.0625f : 1.f;
    ushort* tw = &Tw[w][0];
#pragma unroll
    for (int reg = 0; reg < 16; ++reg) {
      int brow = (reg & 3) + 8 * (reg >> 2) + 4 * half;
      tw[brow * 40 + m31] = f2bf_((acc[reg] + bvv) * scale);
    }
    ushort* dst = (by == 0) ? QF : KF;
    int tile9 = (bh * 32 + ((n0 & 1023) >> 5)) * 9;
    int c0 = ((blockIdx.y * 128 + w * 32) & 127) >> 4;
    int tr = lane >> 1, hb = lane & 1;
#pragma unroll
    for (int cc = 0; cc < 2; ++cc) {
      uint4 v = *(const uint4*)&tw[tr * 40 + cc * 16 + hb * 8];
      *(uint4*)&dst[(size_t)(tile9 + c0 + cc) * 512 + lane * 8] = v;
    }
  }
}

// ---------------------------------------------------------------------------
// Conv1dGLU bf16 MFMA, in-lane GLU, BK=64, split-stage, 4 blocks/CU.
// Block = 64 rows x 64 a-cols (+paired g-cols); grid (256, 4).
// ---------------------------------------------------------------------------
template <int DO_MASK>
__global__ __launch_bounds__(256, 4) void conv_mfma_kernel(
    const ushort* __restrict__ H16, const float* __restrict__ Hf,
    const ushort* __restrict__ WtF, const float* __restrict__ cb,
    const float* __restrict__ fmask, float* __restrict__ outf,
    ushort* __restrict__ outb) {
  __shared__ __align__(16) ushort As[2][68 * 72];
  int tid = threadIdx.x;
  int w = tid >> 6, lane = tid & 63;
  int m31 = lane & 31, half = lane >> 5;
  int wr = w >> 1, wc = w & 1;
  int n0 = blockIdx.x * 64;
  int cg = blockIdx.y;
  int tbase = n0 & 1023;
  int acol = cg * 64 + wc * 32;
  int cotA = cg * 2 + wc, cotG = 8 + cg * 2 + wc;

  floatx16 acc[2];
#pragma unroll
  for (int ct = 0; ct < 2; ++ct)
#pragma unroll
    for (int i = 0; i < 16; ++i) acc[ct][i] = 0.f;

  uint4 ar[3];
  auto loadA = [&](int k0) {
#pragma unroll
    for (int j = 0; j < 3; ++j) {
      int i = tid + j * 256;
      if (i < 544) {
        int row = i >> 3, part = i & 7;
        int t = tbase + row - 2;
        uint4 v = make_uint4(0u, 0u, 0u, 0u);
        if ((unsigned)t < 1024u)
          v = *(const uint4*)&H16[(size_t)(n0 + row - 2) * 256 + k0 + part * 8];
        ar[j] = v;
      }
    }
  };
  auto writeA = [&](int buf) {
#pragma unroll
    for (int j = 0; j < 3; ++j) {
      int i = tid + j * 256;
      if (i < 544) {
        int row = i >> 3, part = i & 7;
        *(uint4*)&As[buf][row * 72 + part * 8] = ar[j];
      }
    }
  };
  loadA(0);
  writeA(0);

  for (int c = 0; c < 4; ++c) {
    __syncthreads();
    if (c < 3) loadA((c + 1) * 64);      // issue loads early
    const ushort* ab = As[c & 1];
#pragma unroll
    for (int tap = 0; tap < 5; ++tap) {
      int fA = ((cotA * 5 + tap) * 8 + c * 2) * 2;
      int fG = ((cotG * 5 + tap) * 8 + c * 2) * 2;
      bf16x8 ba[4], bg[4];
#pragma unroll
      for (int q = 0; q < 4; ++q) {
        ba[q] = *(const bf16x8*)&WtF[(size_t)(fA + q) * 512 + m31 * 16 + half * 8];
        bg[q] = *(const bf16x8*)&WtF[(size_t)(fG + q) * 512 + m31 * 16 + half * 8];
      }
#pragma unroll
      for (int ks = 0; ks < 4; ++ks) {
        bf16x8 af = *(const bf16x8*)&ab[(wr * 32 + m31 + tap) * 72 +
                                        ks * 16 + half * 8];
        acc[0] = __builtin_amdgcn_mfma_f32_32x32x16_bf16(af, ba[ks], acc[0], 0, 0, 0);
        acc[1] = __builtin_amdgcn_mfma_f32_32x32x16_bf16(af, bg[ks], acc[1], 0, 0, 0);
      }
    }
    if (c < 3) writeA((c + 1) & 1);      // write after compute
  }
  int col = acol + m31;
  float ba = cb[col], bg = cb[256 + col];
#pragma unroll
  for (int reg = 0; reg < 16; ++reg) {
    int brow = wr * 32 + (reg & 3) + 8 * (reg >> 2) + 4 * half;
    int grow = n0 + brow;
    float a = acc[0][reg] + ba;
    float g = acc[1][reg] + bg;
    float v = Hf[(size_t)grow * 256 + col] + a * sigmoidf_(g);
    if (DO_MASK) {
      if (fmask[grow] != 0.f) v = 0.f;
    }
    outf[(size_t)grow * 256 + col] = v;
    outb[(size_t)grow * 256 + col] = f2bf_(v);
  }
}

// ---------------------------------------------------------------------------
// bf16 MFMA flash attention with cooperative LDS staging, split-stage:
// next tile's 9 uint4/thread loaded to regs before compute, written after.
// Grid (32 bh, 16 qt); block = 64 q; wave (qt,kh) = 32 q x 512 keys.
// ---------------------------------------------------------------------------
__global__ __launch_bounds__(256, 2) void attn_mfma4_kernel(
    const ushort* __restrict__ QF, const ushort* __restrict__ KF,
    const ushort* __restrict__ VF, ushort* __restrict__ O) {
  __shared__ __align__(16) ushort Sm[2][17408];   // 69632 B
  __shared__ float Ml[2][2][32];
  int tid = threadIdx.x;
  int w = tid >> 6, lane = tid & 63;
  int m31 = lane & 31, half = lane >> 5;
  int qt = w & 1, kh = w >> 1;
  int bh = blockIdx.x;
  int q0 = blockIdx.y * 64 + qt * 32;
  int lpos = m31 * 16 + half * 8;

  bf16x8 qe[9];
  {
    int qtile9 = (bh * 32 + (q0 >> 5)) * 9;
#pragma unroll
    for (int c = 0; c < 9; ++c)
      qe[c] = *(const bf16x8*)&QF[(size_t)(qtile9 + c) * 512 + lpos];
  }
  floatx16 oacc[4];
#pragma unroll
  for (int ct = 0; ct < 4; ++ct)
#pragma unroll
    for (int i = 0; i < 16; ++i) oacc[ct][i] = 0.f;
  float mi = -1e30f, li = 0.f;

  uint4 sreg[9];
  auto loadStage = [&](int it) {
    const ushort* k0src = KF + (size_t)(bh * 32 + it) * 4608;
    const ushort* k1src = KF + (size_t)(bh * 32 + 16 + it) * 4608;
    const ushort* v0src =
        VF + (size_t)((bh * 16 + (it >> 1)) * 16 + (it & 1) * 8) * 512;
    const ushort* v1src =
        VF + (size_t)((bh * 16 + 8 + (it >> 1)) * 16 + (it & 1) * 8) * 512;
#pragma unroll
    for (int k = 0; k < 8; ++k) {
      int c = tid + k * 256;
      const ushort* src;
      int idx;
      if (c < 576)       { src = k0src; idx = c; }
      else if (c < 1152) { src = k1src; idx = c - 576; }
      else if (c < 1664) { src = v0src; idx = c - 1152; }
      else               { src = v1src; idx = c - 1664; }
      sreg[k] = *(const uint4*)(src + idx * 8);
    }
    if (tid < 128) sreg[8] = *(const uint4*)(v1src + (2048 + tid - 1664) * 8);
  };
  auto writeStage = [&](int buf) {
#pragma unroll
    for (int k = 0; k < 8; ++k) {
      int c = tid + k * 256;
      *(uint4*)&Sm[buf][c * 8] = sreg[k];
    }
    if (tid < 128) *(uint4*)&Sm[buf][(2048 + tid) * 8] = sreg[8];
  };

  loadStage(0);
  writeStage(0);
  for (int it = 0; it < 16; ++it) {
    __syncthreads();
    if (it < 15) loadStage(it + 1);      // issue loads early
    int buf = it & 1;
    const ushort* Kb = &Sm[buf][kh * 4608];
    const ushort* Vb = &Sm[buf][9216 + kh * 4096];
    floatx16 s0;
#pragma unroll
    for (int i = 0; i < 16; ++i) s0[i] = 0.f;
#pragma unroll
    for (int c = 0; c < 9; ++c) {
      bf16x8 kf = *(const bf16x8*)&Kb[c * 512 + lpos];
      s0 = __builtin_amdgcn_mfma_f32_32x32x16_bf16(kf, qe[c], s0, 0, 0, 0);
    }
    float mloc = s0[0];
#pragma unroll
    for (int r = 1; r < 16; ++r) mloc = fmaxf(mloc, s0[r]);
    float mt = fmaxf(mloc, __shfl_xor(mloc, 32));
    float mnew = fmaxf(mi, mt);
    float alpha = __expf(mi - mnew);
    bool dead = (mnew <= -3.0e4f);
    float sum = 0.f;
#pragma unroll
    for (int r = 0; r < 16; ++r) {
      float v = dead ? 0.f : __expf(s0[r] - mnew);
      s0[r] = v;
      sum += v;
    }
    sum += __shfl_xor(sum, 32);
    li = li * alpha + sum;
    mi = mnew;
#pragma unroll
    for (int ct = 0; ct < 4; ++ct)
#pragma unroll
      for (int i = 0; i < 16; ++i) oacc[ct][i] *= alpha;
    float tx[16];
#pragma unroll
    for (int r = 0; r < 16; ++r) tx[r] = __shfl_xor(s0[r], 32);
    bf16x8 pf[2];
#pragma unroll
    for (int s = 0; s < 2; ++s) {
      union { bf16x8 v; ushort u[8]; } pk;
#pragma unroll
      for (int j = 0; j < 8; ++j) {
        int base = s * 8;
        float own = s0[base + j];
        float lo = (j < 4) ? own : tx[base + j - 4];
        float hi = (j < 4) ? tx[base + 4 + j] : own;
        pk.u[j] = f2bf_(half ? hi : lo);
      }
      pf[s] = pk.v;
    }
#pragma unroll
    for (int s2 = 0; s2 < 2; ++s2)
#pragma unroll
      for (int ct = 0; ct < 4; ++ct) {
        bf16x8 vf = *(const bf16x8*)&Vb[(s2 * 4 + ct) * 512 + lpos];
        oacc[ct] = __builtin_amdgcn_mfma_f32_32x32x16_bf16(
            vf, pf[s2], oacc[ct], 0, 0, 0);
      }
    if (it < 15) writeStage((it + 1) & 1);   // write after compute
  }
  float* Opf = (float*)&Sm[0][0];   // [2][128][33] overlay
  if (kh == 1) {
#pragma unroll
    for (int ct = 0; ct < 4; ++ct)
#pragma unroll
      for (int r = 0; r < 16; ++r) {
        int dv = ct * 32 + (r & 3) + 8 * (r >> 2) + 4 * half;
        Opf[(qt * 128 + dv) * 33 + m31] = oacc[ct][r];
      }
    if (half == 0) { Ml[qt][0][m31] = mi; Ml[qt][1][m31] = li; }
  }
  __syncthreads();
  if (kh == 0) {
    float mB = Ml[qt][0][m31], lB = Ml[qt][1][m31];
    float m = fmaxf(mi, mB);
    float aA = __expf(mi - m), aB = __expf(mB - m);
    float l = li * aA + lB * aB;
    float inv = (l > 0.f) ? 1.f / l : 0.f;
    int b = bh >> 1, h = bh & 1;
    size_t rowbase = (size_t)(b * 1024 + q0 + m31) * 256 + h * 128;
#pragma unroll
    for (int ct = 0; ct < 4; ++ct)
#pragma unroll
      for (int rg = 0; rg < 4; ++rg) {
        int dv0 = ct * 32 + 8 * rg + 4 * half;
        ushort4 u;
        u.x = f2bf_((oacc[ct][rg * 4 + 0] * aA + Opf[(qt * 128 + dv0 + 0) * 33 + m31] * aB) * inv);
        u.y = f2bf_((oacc[ct][rg * 4 + 1] * aA + Opf[(qt * 128 + dv0 + 1) * 33 + m31] * aB) * inv);
        u.z = f2bf_((oacc[ct][rg * 4 + 2] * aA + Opf[(qt * 128 + dv0 + 2) * 33 + m31] * aB) * inv);
        u.w = f2bf_((oacc[ct][rg * 4 + 3] * aA + Opf[(qt * 128 + dv0 + 3) * 33 + m31] * aB) * inv);
        *(ushort4*)&O[rowbase + dv0] = u;
      }
  }
}

// ---------------------------------------------------------------------------
// Final projection: out[b][j] = dot(pooled[b,:], Wf[j,:]) / len[b] + bf[j].
// ---------------------------------------------------------------------------
__global__ __launch_bounds__(256) void final_kernel(
    const float* __restrict__ pooled, const float* __restrict__ fmask,
    const float* __restrict__ Wf, const float* __restrict__ bf,
    float* __restrict__ out) {
  int b = blockIdx.x, j = threadIdx.x;
  __shared__ __align__(16) float p[256];
  __shared__ float red[256];
  p[j] = pooled[b * 256 + j];
  float c = 0.f;
  for (int i = 0; i < 4; ++i)
    c += (fmask[b * 1024 + i * 256 + j] == 0.f) ? 1.f : 0.f;
  red[j] = c;
  __syncthreads();
  for (int st = 128; st > 0; st >>= 1) {
    if (j < st) red[j] += red[j + st];
    __syncthreads();
  }
  float len = red[0];
  const float* wrow = Wf + (size_t)j * 256;
  float acc = 0.f;
  for (int d4 = 0; d4 < 64; ++d4) {
    float4 wv = ((const float4*)wrow)[d4];
    float4 pv = ((const float4*)p)[d4];
    acc += wv.x * pv.x + wv.y * pv.y + wv.z * pv.z + wv.w * pv.w;
  }
  float inv = (len > 0.f) ? 1.f / len : 0.f;
  out[b * 256 + j] = acc * inv + bf[j];
}

// ---------------------------------------------------------------------------
extern "C" void kernel_launch(void* const* d_in, const int* in_sizes, int n_in,
                              void* d_out, int out_size, void* d_ws, size_t ws_size,
                              hipStream_t stream) {
  const float* x      = (const float*)d_in[0];
  const unsigned* msk = (const unsigned*)d_in[1];
  const float* W1 = (const float*)d_in[2];
  const float* b1 = (const float*)d_in[3];
  const float* W2 = (const float*)d_in[4];
  const float* b2 = (const float*)d_in[5];
  const float* cW1 = (const float*)d_in[6];
  const float* cb1 = (const float*)d_in[7];
  const float* cW2 = (const float*)d_in[8];
  const float* cb2 = (const float*)d_in[9];
  const float* Wq = (const float*)d_in[10];
  const float* bq = (const float*)d_in[11];
  const float* Wk = (const float*)d_in[12];
  const float* bk = (const float*)d_in[13];
  const float* Wv = (const float*)d_in[14];
  const float* bv = (const float*)d_in[15];
  const float* Wo = (const float*)d_in[16];
  const float* bo = (const float*)d_in[17];
  const float* Wf = (const float*)d_in[18];
  const float* bf = (const float*)d_in[19];
  float* out = (float*)d_out;

  float* ws = (float*)d_ws;
  size_t ND = (size_t)N_ * D_;  // 4194304
  float* F0      = ws;
  float* F1      = F0 + ND;
  float* fmask   = F1 + ND;
  float* pooled  = fmask + N_;           // [16*256]
  ushort* G0 = (ushort*)(pooled + 16 * 256);
  ushort* G1 = G0 + ND;
  ushort* QF = G1 + ND;                  // [32*32*9*512]
  ushort* KF = QF + (size_t)32 * 32 * 9 * 512;
  ushort* VF = KF + (size_t)32 * 32 * 9 * 512; // [32*16*16*512]
  ushort* w1_16 = VF + (size_t)32 * 16 * 16 * 512;
  ushort* w2_16 = w1_16 + 65536;
  ushort* wo_16 = w2_16 + 65536;
  ushort* wqkv  = wo_16 + 65536;         // 3 x 65536
  ushort* WtF1  = wqkv + 3 * 65536;      // [655360]
  ushort* WtF2  = WtF1 + 655360;

  dim3 blk(256);
  prep_all_kernel<<<dim3(1152), blk, 0, stream>>>(
      msk, W1, W2, Wq, Wk, Wv, Wo, cW1, cW2,
      w1_16, w2_16, wqkv, wo_16, WtF1, WtF2, fmask, QF, KF, pooled);
  // spectral MLP (MLP1 reads fp32 x directly, converting during staging)
  gemm_mfma_kernel<1, 0, 1, 1><<<dim3(512, 2), blk, 0, stream>>>(
      x, w1_16, b1, nullptr, nullptr, nullptr, G1);
  gemm_mfma_kernel<1, 0, 2, 0><<<dim3(512, 2), blk, 0, stream>>>(
      G1, w2_16, b2, nullptr, nullptr, F0, G0);
  // conv GLU x2 (second fuses mask-zeroing)
  conv_mfma_kernel<0><<<dim3(256, 4), blk, 0, stream>>>(
      G0, F0, WtF1, cb1, fmask, F1, G1);
  conv_mfma_kernel<1><<<dim3(256, 4), blk, 0, stream>>>(
      G1, F1, WtF2, cb2, fmask, F0, G0);
  // fused QKV into QF/KF/VF frag-major layouts
  qkv_mfma_kernel<<<dim3(512, 2, 3), blk, 0, stream>>>(
      G0, wqkv, bq, bk, bv, QF, KF, VF);
  // attention (LDS-staged split-stage pipeline, XCD-aware grid)
  attn_mfma4_kernel<<<dim3(32, 16), blk, 0, stream>>>(QF, KF, VF, G1);
  // out-proj + residual + masked pooling (h5 never materialized)
  gemm_mfma_kernel<0, 1, 3, 0><<<dim3(512, 2), blk, 0, stream>>>(
      G1, wo_16, bo, F0, fmask, pooled, nullptr);
  // final projection
  final_kernel<<<dim3(16), blk, 0, stream>>>(pooled, fmask, Wf, bf, out);
}

// Round 13
// 272.368 us; speedup vs baseline: 1.1874x; 1.1874x over previous
//
#include <hip/hip_runtime.h>
#include <hip/hip_bf16.h>
#include <math.h>

// ============================================================================
// StylePredictor. Round 13: round-12 split-stage gemm/qkv/conv (worth ~12us)
// + round-11 attention reverted (spill-free stage(): load->ds_write inside
// the staging pass, no registers held across compute). Best-of-both.
// ============================================================================

#define DEV __device__ __forceinline__

static constexpr int B_ = 16, T_ = 1024, D_ = 256;
static constexpr int N_ = B_ * T_;

typedef __attribute__((ext_vector_type(8))) short bf16x8;
typedef __attribute__((ext_vector_type(16))) float floatx16;

DEV float sigmoidf_(float x) { return 1.f / (1.f + __expf(-x)); }
// mish(x) = x*tanh(softplus(x)) = x * t/(t+2), t = u*(u+2), u = e^x
DEV float mishf_(float x) {
  float u = __expf(fminf(x, 30.f));
  float t = u * (u + 2.f);
  return x * (t / (t + 2.f));
}
DEV ushort f2bf_(float x) {
  __hip_bfloat16 h = __float2bfloat16(x);
  return *(ushort*)&h;
}

// ---------------------------------------------------------------------------
// Mega-prep (unchanged).
// ---------------------------------------------------------------------------
__global__ __launch_bounds__(256) void prep_all_kernel(
    const unsigned* __restrict__ mraw,
    const float* __restrict__ W1, const float* __restrict__ W2,
    const float* __restrict__ Wq, const float* __restrict__ Wk,
    const float* __restrict__ Wv, const float* __restrict__ Wo,
    const float* __restrict__ cW1, const float* __restrict__ cW2,
    ushort* __restrict__ w1, ushort* __restrict__ w2,
    ushort* __restrict__ wqkv, ushort* __restrict__ wo,
    ushort* __restrict__ WtF1, ushort* __restrict__ WtF2,
    float* __restrict__ fmask, ushort* __restrict__ QF,
    ushort* __restrict__ KF, float* __restrict__ pooled) {
  int bid = blockIdx.x, tid = threadIdx.x;
  if (bid < 384) {
    int i = bid * 256 + tid;  // 0..98303
    int widx = i >> 14, r = i & 16383;
    const float* src;
    ushort* dst;
    switch (widx) {
      case 0: src = W1; dst = w1; break;
      case 1: src = W2; dst = w2; break;
      case 2: src = Wq; dst = wqkv; break;
      case 3: src = Wk; dst = wqkv + 65536; break;
      case 4: src = Wv; dst = wqkv + 131072; break;
      default: src = Wo; dst = wo; break;
    }
    float4 v = ((const float4*)src)[r];
    ushort4 u;
    u.x = f2bf_(v.x); u.y = f2bf_(v.y); u.z = f2bf_(v.z); u.w = f2bf_(v.w);
    ((ushort4*)dst)[r] = u;
  } else if (bid < 1024) {
    int idx = (bid - 384) * 256 + tid;  // 0..163839 (ushort8 granules)
    const float* cw = (idx < 81920) ? cW1 : cW2;
    ushort* dst = (idx < 81920) ? WtF1 : WtF2;
    int i8 = (idx < 81920) ? idx : idx - 81920;
    int i = i8 * 8;
    int half = (i >> 3) & 1, m31 = (i >> 4) & 31;
    int frag = i >> 9;
    int ks = frag & 1, c = (frag >> 1) & 7, tap = (frag >> 4) % 5,
        cot = frag / 80;
    int co = cot * 32 + m31;
    int cin0 = c * 32 + ks * 16 + half * 8;
    ushort u[8];
#pragma unroll
    for (int j = 0; j < 8; ++j)
      u[j] = f2bf_(cw[(size_t)(co * 256 + cin0 + j) * 5 + tap]);
    *(uint4*)&dst[i] = *(uint4*)u;
  } else {
    // mask detection + fmask + QF/KF bias chunks + pooled zero
    int isByte = 0, isFloat = 0;
    for (int i = 0; i < 16; ++i) {
      unsigned v = mraw[tid * 16 + i];
      if (v == 0x3F800000u) isFloat = 1;
      else if (v > 1u) isByte = 1;
    }
    __shared__ int sByte, sFloat;
    if (tid == 0) { sByte = 0; sFloat = 0; }
    __syncthreads();
    if (isByte) atomicOr(&sByte, 1);
    if (isFloat) atomicOr(&sFloat, 1);
    __syncthreads();
    int mode = sFloat ? 2 : (sByte ? 1 : 0);
    int mb = bid - 1024;                 // 0..127
    int id = mb * 256 + tid;             // bh*1024 + t
    int bh = id >> 10, t = id & 1023, b = bh >> 1;
    int gidx = b * 1024 + t;
    unsigned mv;
    if (mode == 1) mv = ((const unsigned char*)mraw)[gidx];
    else           mv = mraw[gidx];
    float fm = (mv != 0u) ? 1.f : 0.f;
    if ((bh & 1) == 0) fmask[gidx] = fm;
    if (mb < 16) pooled[mb * 256 + tid] = 0.f;
    size_t qb = ((size_t)(bh * 32 + (t >> 5)) * 9 + 8) * 512 + (t & 31) * 16;
    QF[qb] = f2bf_(1.f);
#pragma unroll
    for (int j = 1; j < 16; ++j) QF[qb + j] = 0;
    size_t kb = ((size_t)(bh * 32 + (t >> 5)) * 9 + 8) * 512 + (t & 31) * 16;
    KF[kb] = (fm != 0.f) ? f2bf_(-60000.f) : (ushort)0;
#pragma unroll
    for (int j = 1; j < 16; ++j) KF[kb + j] = 0;
  }
}

// ---------------------------------------------------------------------------
// bf16 MFMA GEMM, BK=64, split-stage pipeline (round-12 version).
// ---------------------------------------------------------------------------
template <int ACT, int RESID, int OMODE, int AF32>
__global__ __launch_bounds__(256, 4) void gemm_mfma_kernel(
    const void* __restrict__ Av, const ushort* __restrict__ W16,
    const float* __restrict__ bias, const float* __restrict__ resid,
    const float* __restrict__ fmask,
    float* __restrict__ outf, ushort* __restrict__ outb) {
  __shared__ __align__(16) ushort As[2][32 * 72];
  int tid = threadIdx.x;
  int w = tid >> 6, lane = tid & 63;
  int m31 = lane & 31, half = lane >> 5;
  int n0 = blockIdx.x * 32;
  int col = blockIdx.y * 128 + w * 32 + m31;
  const ushort* A16 = (const ushort*)Av;
  const float* A32 = (const float*)Av;
  int srow = tid >> 3, spart = tid & 7;

  floatx16 acc;
#pragma unroll
  for (int i = 0; i < 16; ++i) acc[i] = 0.f;

  uint4 areg;
  float4 af0, af1;
  auto loadA = [&](int k0) {
    if (AF32) {
      af0 = *(const float4*)&A32[(size_t)(n0 + srow) * 256 + k0 + spart * 8];
      af1 = *(const float4*)&A32[(size_t)(n0 + srow) * 256 + k0 + spart * 8 + 4];
    } else {
      areg = *(const uint4*)&A16[(size_t)(n0 + srow) * 256 + k0 + spart * 8];
    }
  };
  auto writeA = [&](int buf) {
    if (AF32) {
      ushort u[8];
      u[0] = f2bf_(af0.x); u[1] = f2bf_(af0.y); u[2] = f2bf_(af0.z); u[3] = f2bf_(af0.w);
      u[4] = f2bf_(af1.x); u[5] = f2bf_(af1.y); u[6] = f2bf_(af1.z); u[7] = f2bf_(af1.w);
      *(uint4*)&As[buf][srow * 72 + spart * 8] = *(uint4*)u;
    } else {
      *(uint4*)&As[buf][srow * 72 + spart * 8] = areg;
    }
  };
  loadA(0);
  writeA(0);
  bf16x8 bn[4];
#pragma unroll
  for (int ks = 0; ks < 4; ++ks)
    bn[ks] = *(const bf16x8*)&W16[(size_t)col * 256 + ks * 16 + half * 8];

  for (int c = 0; c < 4; ++c) {
    __syncthreads();
    if (c < 3) loadA((c + 1) * 64);      // issue loads early
    bf16x8 bc[4] = {bn[0], bn[1], bn[2], bn[3]};
    if (c < 3) {
      int k0 = (c + 1) * 64;
#pragma unroll
      for (int ks = 0; ks < 4; ++ks)
        bn[ks] = *(const bf16x8*)&W16[(size_t)col * 256 + k0 + ks * 16 + half * 8];
    }
    const ushort* ab = As[c & 1];
#pragma unroll
    for (int ks = 0; ks < 4; ++ks) {
      bf16x8 af = *(const bf16x8*)&ab[m31 * 72 + ks * 16 + half * 8];
      acc = __builtin_amdgcn_mfma_f32_32x32x16_bf16(af, bc[ks], acc, 0, 0, 0);
    }
    if (c < 3) writeA((c + 1) & 1);      // write after compute
  }
  float bv = bias[col];
  if (OMODE == 3) {
    int b = n0 >> 10;
    float psum = 0.f;
#pragma unroll
    for (int reg = 0; reg < 16; ++reg) {
      int row = n0 + (reg & 3) + 8 * (reg >> 2) + 4 * half;
      float keep = (fmask[row] == 0.f) ? 1.f : 0.f;
      psum += keep * (acc[reg] + bv + resid[(size_t)row * 256 + col]);
    }
    atomicAdd(&outf[b * 256 + col], psum);
    return;
  }
#pragma unroll
  for (int reg = 0; reg < 16; ++reg) {
    int row = n0 + (reg & 3) + 8 * (reg >> 2) + 4 * half;
    float v = acc[reg] + bv;
    if (ACT == 1) v = mishf_(v);
    if (RESID) v += resid[(size_t)row * 256 + col];
    if (OMODE == 0) {
      outf[(size_t)row * 256 + col] = v;
    } else if (OMODE == 1) {
      outb[(size_t)row * 256 + col] = f2bf_(v);
    } else {
      outf[(size_t)row * 256 + col] = v;
      outb[(size_t)row * 256 + col] = f2bf_(v);
    }
  }
}

// ---------------------------------------------------------------------------
// Fused QKV projection, BK=64, split-stage (round-12 version).
// ---------------------------------------------------------------------------
__global__ __launch_bounds__(256, 4) void qkv_mfma_kernel(
    const ushort* __restrict__ A16, const ushort* __restrict__ wqkv,
    const float* __restrict__ bq, const float* __restrict__ bk,
    const float* __restrict__ bv,
    ushort* __restrict__ QF, ushort* __restrict__ KF, ushort* __restrict__ VF) {
  __shared__ __align__(16) ushort As[2][32 * 72];
  __shared__ __align__(16) ushort Tw[4][32 * 40];
  int tid = threadIdx.x;
  int w = tid >> 6, lane = tid & 63;
  int m31 = lane & 31, half = lane >> 5;
  int n0 = blockIdx.x * 32;
  int by = blockIdx.z;
  const ushort* W16 = wqkv + (size_t)by * 65536;
  const float* bias = (by == 0) ? bq : (by == 1) ? bk : bv;
  int col = blockIdx.y * 128 + w * 32 + m31;
  int srow = tid >> 3, spart = tid & 7;

  floatx16 acc;
#pragma unroll
  for (int i = 0; i < 16; ++i) acc[i] = 0.f;

  uint4 areg = *(const uint4*)&A16[(size_t)(n0 + srow) * 256 + spart * 8];
  *(uint4*)&As[0][srow * 72 + spart * 8] = areg;
  bf16x8 bn[4];
#pragma unroll
  for (int ks = 0; ks < 4; ++ks)
    bn[ks] = *(const bf16x8*)&W16[(size_t)col * 256 + ks * 16 + half * 8];

  for (int c = 0; c < 4; ++c) {
    __syncthreads();
    if (c < 3) {
      int k0 = (c + 1) * 64;
      areg = *(const uint4*)&A16[(size_t)(n0 + srow) * 256 + k0 + spart * 8];
    }
    bf16x8 bc[4] = {bn[0], bn[1], bn[2], bn[3]};
    if (c < 3) {
      int k0 = (c + 1) * 64;
#pragma unroll
      for (int ks = 0; ks < 4; ++ks)
        bn[ks] = *(const bf16x8*)&W16[(size_t)col * 256 + k0 + ks * 16 + half * 8];
    }
    const ushort* ab = As[c & 1];
#pragma unroll
    for (int ks = 0; ks < 4; ++ks) {
      bf16x8 af = *(const bf16x8*)&ab[m31 * 72 + ks * 16 + half * 8];
      acc = __builtin_amdgcn_mfma_f32_32x32x16_bf16(af, bc[ks], acc, 0, 0, 0);
    }
    if (c < 3) *(uint4*)&As[(c + 1) & 1][srow * 72 + spart * 8] = areg;
  }
  int b = n0 >> 10;
  float bvv = bias[col];
  int h = col >> 7, d127 = col & 127;
  int bh = b * 2 + h;
  if (by == 2) {  // VF frag-major, ushort4 stores (already coalesced)
    int ctv = d127 >> 5, m31v = d127 & 31;
#pragma unroll
    for (int rg = 0; rg < 4; ++rg) {
      int t0 = (n0 & 1023) + 8 * rg + 4 * half;
      ushort4 u;
      u.x = f2bf_(acc[rg * 4 + 0] + bvv);
      u.y = f2bf_(acc[rg * 4 + 1] + bvv);
      u.z = f2bf_(acc[rg * 4 + 2] + bvv);
      u.w = f2bf_(acc[rg * 4 + 3] + bvv);
      size_t addr = ((size_t)(bh * 16 + (t0 >> 6)) * 16 +
                     ((t0 >> 4) & 3) * 4 + ctv) * 512 +
                    m31v * 16 + ((t0 >> 3) & 1) * 8 + (t0 & 7);
      *(ushort4*)&VF[addr] = u;
    }
  } else {
    float scale = (by == 0) ? 0.0625f : 1.f;
    ushort* tw = &Tw[w][0];
#pragma unroll
    for (int reg = 0; reg < 16; ++reg) {
      int brow = (reg & 3) + 8 * (reg >> 2) + 4 * half;
      tw[brow * 40 + m31] = f2bf_((acc[reg] + bvv) * scale);
    }
    ushort* dst = (by == 0) ? QF : KF;
    int tile9 = (bh * 32 + ((n0 & 1023) >> 5)) * 9;
    int c0 = ((blockIdx.y * 128 + w * 32) & 127) >> 4;
    int tr = lane >> 1, hb = lane & 1;
#pragma unroll
    for (int cc = 0; cc < 2; ++cc) {
      uint4 v = *(const uint4*)&tw[tr * 40 + cc * 16 + hb * 8];
      *(uint4*)&dst[(size_t)(tile9 + c0 + cc) * 512 + lane * 8] = v;
    }
  }
}

// ---------------------------------------------------------------------------
// Conv1dGLU bf16 MFMA, in-lane GLU, BK=64, split-stage (round-12 version).
// ---------------------------------------------------------------------------
template <int DO_MASK>
__global__ __launch_bounds__(256, 4) void conv_mfma_kernel(
    const ushort* __restrict__ H16, const float* __restrict__ Hf,
    const ushort* __restrict__ WtF, const float* __restrict__ cb,
    const float* __restrict__ fmask, float* __restrict__ outf,
    ushort* __restrict__ outb) {
  __shared__ __align__(16) ushort As[2][68 * 72];
  int tid = threadIdx.x;
  int w = tid >> 6, lane = tid & 63;
  int m31 = lane & 31, half = lane >> 5;
  int wr = w >> 1, wc = w & 1;
  int n0 = blockIdx.x * 64;
  int cg = blockIdx.y;
  int tbase = n0 & 1023;
  int acol = cg * 64 + wc * 32;
  int cotA = cg * 2 + wc, cotG = 8 + cg * 2 + wc;

  floatx16 acc[2];
#pragma unroll
  for (int ct = 0; ct < 2; ++ct)
#pragma unroll
    for (int i = 0; i < 16; ++i) acc[ct][i] = 0.f;

  uint4 ar[3];
  auto loadA = [&](int k0) {
#pragma unroll
    for (int j = 0; j < 3; ++j) {
      int i = tid + j * 256;
      if (i < 544) {
        int row = i >> 3, part = i & 7;
        int t = tbase + row - 2;
        uint4 v = make_uint4(0u, 0u, 0u, 0u);
        if ((unsigned)t < 1024u)
          v = *(const uint4*)&H16[(size_t)(n0 + row - 2) * 256 + k0 + part * 8];
        ar[j] = v;
      }
    }
  };
  auto writeA = [&](int buf) {
#pragma unroll
    for (int j = 0; j < 3; ++j) {
      int i = tid + j * 256;
      if (i < 544) {
        int row = i >> 3, part = i & 7;
        *(uint4*)&As[buf][row * 72 + part * 8] = ar[j];
      }
    }
  };
  loadA(0);
  writeA(0);

  for (int c = 0; c < 4; ++c) {
    __syncthreads();
    if (c < 3) loadA((c + 1) * 64);
    const ushort* ab = As[c & 1];
#pragma unroll
    for (int tap = 0; tap < 5; ++tap) {
      int fA = ((cotA * 5 + tap) * 8 + c * 2) * 2;
      int fG = ((cotG * 5 + tap) * 8 + c * 2) * 2;
      bf16x8 ba[4], bg[4];
#pragma unroll
      for (int q = 0; q < 4; ++q) {
        ba[q] = *(const bf16x8*)&WtF[(size_t)(fA + q) * 512 + m31 * 16 + half * 8];
        bg[q] = *(const bf16x8*)&WtF[(size_t)(fG + q) * 512 + m31 * 16 + half * 8];
      }
#pragma unroll
      for (int ks = 0; ks < 4; ++ks) {
        bf16x8 af = *(const bf16x8*)&ab[(wr * 32 + m31 + tap) * 72 +
                                        ks * 16 + half * 8];
        acc[0] = __builtin_amdgcn_mfma_f32_32x32x16_bf16(af, ba[ks], acc[0], 0, 0, 0);
        acc[1] = __builtin_amdgcn_mfma_f32_32x32x16_bf16(af, bg[ks], acc[1], 0, 0, 0);
      }
    }
    if (c < 3) writeA((c + 1) & 1);
  }
  int col = acol + m31;
  float ba = cb[col], bg = cb[256 + col];
#pragma unroll
  for (int reg = 0; reg < 16; ++reg) {
    int brow = wr * 32 + (reg & 3) + 8 * (reg >> 2) + 4 * half;
    int grow = n0 + brow;
    float a = acc[0][reg] + ba;
    float g = acc[1][reg] + bg;
    float v = Hf[(size_t)grow * 256 + col] + a * sigmoidf_(g);
    if (DO_MASK) {
      if (fmask[grow] != 0.f) v = 0.f;
    }
    outf[(size_t)grow * 256 + col] = v;
    outb[(size_t)grow * 256 + col] = f2bf_(v);
  }
}

// ---------------------------------------------------------------------------
// bf16 MFMA flash attention, cooperative LDS staging (round-11 spill-free
// form: load->ds_write inside stage(), no registers held across compute).
// Grid (32 bh, 16 qt); block = 64 q; wave (qt,kh) = 32 q x 512 keys.
// ---------------------------------------------------------------------------
__global__ __launch_bounds__(256, 2) void attn_mfma4_kernel(
    const ushort* __restrict__ QF, const ushort* __restrict__ KF,
    const ushort* __restrict__ VF, ushort* __restrict__ O) {
  __shared__ __align__(16) ushort Sm[2][17408];   // 69632 B
  __shared__ float Ml[2][2][32];
  int tid = threadIdx.x;
  int w = tid >> 6, lane = tid & 63;
  int m31 = lane & 31, half = lane >> 5;
  int qt = w & 1, kh = w >> 1;
  int bh = blockIdx.x;
  int q0 = blockIdx.y * 64 + qt * 32;
  int lpos = m31 * 16 + half * 8;

  bf16x8 qe[9];
  {
    int qtile9 = (bh * 32 + (q0 >> 5)) * 9;
#pragma unroll
    for (int c = 0; c < 9; ++c)
      qe[c] = *(const bf16x8*)&QF[(size_t)(qtile9 + c) * 512 + lpos];
  }
  floatx16 oacc[4];
#pragma unroll
  for (int ct = 0; ct < 4; ++ct)
#pragma unroll
    for (int i = 0; i < 16; ++i) oacc[ct][i] = 0.f;
  float mi = -1e30f, li = 0.f;

  auto stage = [&](int it, int buf) {
    const ushort* k0src = KF + (size_t)(bh * 32 + it) * 4608;
    const ushort* k1src = KF + (size_t)(bh * 32 + 16 + it) * 4608;
    const ushort* v0src =
        VF + (size_t)((bh * 16 + (it >> 1)) * 16 + (it & 1) * 8) * 512;
    const ushort* v1src =
        VF + (size_t)((bh * 16 + 8 + (it >> 1)) * 16 + (it & 1) * 8) * 512;
    auto copyc = [&](int c) {
      const ushort* src;
      int idx;
      if (c < 576)       { src = k0src; idx = c; }
      else if (c < 1152) { src = k1src; idx = c - 576; }
      else if (c < 1664) { src = v0src; idx = c - 1152; }
      else               { src = v1src; idx = c - 1664; }
      uint4 v = *(const uint4*)(src + idx * 8);
      *(uint4*)&Sm[buf][c * 8] = v;
    };
#pragma unroll
    for (int k = 0; k < 8; ++k) copyc(tid + k * 256);
    if (tid < 128) copyc(2048 + tid);
  };

  stage(0, 0);
  for (int it = 0; it < 16; ++it) {
    __syncthreads();
    int buf = it & 1;
    const ushort* Kb = &Sm[buf][kh * 4608];
    const ushort* Vb = &Sm[buf][9216 + kh * 4096];
    floatx16 s0;
#pragma unroll
    for (int i = 0; i < 16; ++i) s0[i] = 0.f;
#pragma unroll
    for (int c = 0; c < 9; ++c) {
      bf16x8 kf = *(const bf16x8*)&Kb[c * 512 + lpos];
      s0 = __builtin_amdgcn_mfma_f32_32x32x16_bf16(kf, qe[c], s0, 0, 0, 0);
    }
    float mloc = s0[0];
#pragma unroll
    for (int r = 1; r < 16; ++r) mloc = fmaxf(mloc, s0[r]);
    float mt = fmaxf(mloc, __shfl_xor(mloc, 32));
    float mnew = fmaxf(mi, mt);
    float alpha = __expf(mi - mnew);
    bool dead = (mnew <= -3.0e4f);
    float sum = 0.f;
#pragma unroll
    for (int r = 0; r < 16; ++r) {
      float v = dead ? 0.f : __expf(s0[r] - mnew);
      s0[r] = v;
      sum += v;
    }
    sum += __shfl_xor(sum, 32);
    li = li * alpha + sum;
    mi = mnew;
#pragma unroll
    for (int ct = 0; ct < 4; ++ct)
#pragma unroll
      for (int i = 0; i < 16; ++i) oacc[ct][i] *= alpha;
    float tx[16];
#pragma unroll
    for (int r = 0; r < 16; ++r) tx[r] = __shfl_xor(s0[r], 32);
    bf16x8 pf[2];
#pragma unroll
    for (int s = 0; s < 2; ++s) {
      union { bf16x8 v; ushort u[8]; } pk;
#pragma unroll
      for (int j = 0; j < 8; ++j) {
        int base = s * 8;
        float own = s0[base + j];
        float lo = (j < 4) ? own : tx[base + j - 4];
        float hi = (j < 4) ? tx[base + 4 + j] : own;
        pk.u[j] = f2bf_(half ? hi : lo);
      }
      pf[s] = pk.v;
    }
#pragma unroll
    for (int s2 = 0; s2 < 2; ++s2)
#pragma unroll
      for (int ct = 0; ct < 4; ++ct) {
        bf16x8 vf = *(const bf16x8*)&Vb[(s2 * 4 + ct) * 512 + lpos];
        oacc[ct] = __builtin_amdgcn_mfma_f32_32x32x16_bf16(
            vf, pf[s2], oacc[ct], 0, 0, 0);
      }
    if (it < 15) stage(it + 1, (it + 1) & 1);
  }
  float* Opf = (float*)&Sm[0][0];   // [2][128][33] overlay
  if (kh == 1) {
#pragma unroll
    for (int ct = 0; ct < 4; ++ct)
#pragma unroll
      for (int r = 0; r < 16; ++r) {
        int dv = ct * 32 + (r & 3) + 8 * (r >> 2) + 4 * half;
        Opf[(qt * 128 + dv) * 33 + m31] = oacc[ct][r];
      }
    if (half == 0) { Ml[qt][0][m31] = mi; Ml[qt][1][m31] = li; }
  }
  __syncthreads();
  if (kh == 0) {
    float mB = Ml[qt][0][m31], lB = Ml[qt][1][m31];
    float m = fmaxf(mi, mB);
    float aA = __expf(mi - m), aB = __expf(mB - m);
    float l = li * aA + lB * aB;
    float inv = (l > 0.f) ? 1.f / l : 0.f;
    int b = bh >> 1, h = bh & 1;
    size_t rowbase = (size_t)(b * 1024 + q0 + m31) * 256 + h * 128;
#pragma unroll
    for (int ct = 0; ct < 4; ++ct)
#pragma unroll
      for (int rg = 0; rg < 4; ++rg) {
        int dv0 = ct * 32 + 8 * rg + 4 * half;
        ushort4 u;
        u.x = f2bf_((oacc[ct][rg * 4 + 0] * aA + Opf[(qt * 128 + dv0 + 0) * 33 + m31] * aB) * inv);
        u.y = f2bf_((oacc[ct][rg * 4 + 1] * aA + Opf[(qt * 128 + dv0 + 1) * 33 + m31] * aB) * inv);
        u.z = f2bf_((oacc[ct][rg * 4 + 2] * aA + Opf[(qt * 128 + dv0 + 2) * 33 + m31] * aB) * inv);
        u.w = f2bf_((oacc[ct][rg * 4 + 3] * aA + Opf[(qt * 128 + dv0 + 3) * 33 + m31] * aB) * inv);
        *(ushort4*)&O[rowbase + dv0] = u;
      }
  }
}

// ---------------------------------------------------------------------------
// Final projection: out[b][j] = dot(pooled[b,:], Wf[j,:]) / len[b] + bf[j].
// ---------------------------------------------------------------------------
__global__ __launch_bounds__(256) void final_kernel(
    const float* __restrict__ pooled, const float* __restrict__ fmask,
    const float* __restrict__ Wf, const float* __restrict__ bf,
    float* __restrict__ out) {
  int b = blockIdx.x, j = threadIdx.x;
  __shared__ __align__(16) float p[256];
  __shared__ float red[256];
  p[j] = pooled[b * 256 + j];
  float c = 0.f;
  for (int i = 0; i < 4; ++i)
    c += (fmask[b * 1024 + i * 256 + j] == 0.f) ? 1.f : 0.f;
  red[j] = c;
  __syncthreads();
  for (int st = 128; st > 0; st >>= 1) {
    if (j < st) red[j] += red[j + st];
    __syncthreads();
  }
  float len = red[0];
  const float* wrow = Wf + (size_t)j * 256;
  float acc = 0.f;
  for (int d4 = 0; d4 < 64; ++d4) {
    float4 wv = ((const float4*)wrow)[d4];
    float4 pv = ((const float4*)p)[d4];
    acc += wv.x * pv.x + wv.y * pv.y + wv.z * pv.z + wv.w * pv.w;
  }
  float inv = (len > 0.f) ? 1.f / len : 0.f;
  out[b * 256 + j] = acc * inv + bf[j];
}

// ---------------------------------------------------------------------------
extern "C" void kernel_launch(void* const* d_in, const int* in_sizes, int n_in,
                              void* d_out, int out_size, void* d_ws, size_t ws_size,
                              hipStream_t stream) {
  const float* x      = (const float*)d_in[0];
  const unsigned* msk = (const unsigned*)d_in[1];
  const float* W1 = (const float*)d_in[2];
  const float* b1 = (const float*)d_in[3];
  const float* W2 = (const float*)d_in[4];
  const float* b2 = (const float*)d_in[5];
  const float* cW1 = (const float*)d_in[6];
  const float* cb1 = (const float*)d_in[7];
  const float* cW2 = (const float*)d_in[8];
  const float* cb2 = (const float*)d_in[9];
  const float* Wq = (const float*)d_in[10];
  const float* bq = (const float*)d_in[11];
  const float* Wk = (const float*)d_in[12];
  const float* bk = (const float*)d_in[13];
  const float* Wv = (const float*)d_in[14];
  const float* bv = (const float*)d_in[15];
  const float* Wo = (const float*)d_in[16];
  const float* bo = (const float*)d_in[17];
  const float* Wf = (const float*)d_in[18];
  const float* bf = (const float*)d_in[19];
  float* out = (float*)d_out;

  float* ws = (float*)d_ws;
  size_t ND = (size_t)N_ * D_;  // 4194304
  float* F0      = ws;
  float* F1      = F0 + ND;
  float* fmask   = F1 + ND;
  float* pooled  = fmask + N_;           // [16*256]
  ushort* G0 = (ushort*)(pooled + 16 * 256);
  ushort* G1 = G0 + ND;
  ushort* QF = G1 + ND;                  // [32*32*9*512]
  ushort* KF = QF + (size_t)32 * 32 * 9 * 512;
  ushort* VF = KF + (size_t)32 * 32 * 9 * 512; // [32*16*16*512]
  ushort* w1_16 = VF + (size_t)32 * 16 * 16 * 512;
  ushort* w2_16 = w1_16 + 65536;
  ushort* wo_16 = w2_16 + 65536;
  ushort* wqkv  = wo_16 + 65536;         // 3 x 65536
  ushort* WtF1  = wqkv + 3 * 65536;      // [655360]
  ushort* WtF2  = WtF1 + 655360;

  dim3 blk(256);
  prep_all_kernel<<<dim3(1152), blk, 0, stream>>>(
      msk, W1, W2, Wq, Wk, Wv, Wo, cW1, cW2,
      w1_16, w2_16, wqkv, wo_16, WtF1, WtF2, fmask, QF, KF, pooled);
  // spectral MLP (MLP1 reads fp32 x directly, converting during staging)
  gemm_mfma_kernel<1, 0, 1, 1><<<dim3(512, 2), blk, 0, stream>>>(
      x, w1_16, b1, nullptr, nullptr, nullptr, G1);
  gemm_mfma_kernel<1, 0, 2, 0><<<dim3(512, 2), blk, 0, stream>>>(
      G1, w2_16, b2, nullptr, nullptr, F0, G0);
  // conv GLU x2 (second fuses mask-zeroing)
  conv_mfma_kernel<0><<<dim3(256, 4), blk, 0, stream>>>(
      G0, F0, WtF1, cb1, fmask, F1, G1);
  conv_mfma_kernel<1><<<dim3(256, 4), blk, 0, stream>>>(
      G1, F1, WtF2, cb2, fmask, F0, G0);
  // fused QKV into QF/KF/VF frag-major layouts
  qkv_mfma_kernel<<<dim3(512, 2, 3), blk, 0, stream>>>(
      G0, wqkv, bq, bk, bv, QF, KF, VF);
  // attention (round-11 spill-free LDS-staged pipeline, XCD-aware grid)
  attn_mfma4_kernel<<<dim3(32, 16), blk, 0, stream>>>(QF, KF, VF, G1);
  // out-proj + residual + masked pooling (h5 never materialized)
  gemm_mfma_kernel<0, 1, 3, 0><<<dim3(512, 2), blk, 0, stream>>>(
      G1, wo_16, bo, F0, fmask, pooled, nullptr);
  // final projection
  final_kernel<<<dim3(16), blk, 0, stream>>>(pooled, fmask, Wf, bf, out);
}